// Round 1
// baseline (273.941 us; speedup 1.0000x reference)
//
#include <hip/hip_runtime.h>
#include <hip/hip_bf16.h>

// GDGCN: out[b,c,m,t] = sum_n softmax_row(relu(t1 nv2^T))[n,m] * x[b,c,n,t]
// t1 = nv1 @ (sum_d tv[d] k[d,:,:]);  N=8192, D=32, cols = B*C*T = 192.
// Fused flash-style: never materialize the 8192x8192 adjacency.

#define NN 8192
#define DD 32
#define TT 12
#define NCOLS 192

typedef __attribute__((ext_vector_type(8))) short bf16x8;
typedef __attribute__((ext_vector_type(4))) float f32x4;

static __device__ __forceinline__ unsigned short f2bf(float f) {
  unsigned int u = __float_as_uint(f);
  u = (u + 0x7FFFu + ((u >> 16) & 1u)) >> 16;  // RNE bf16
  return (unsigned short)u;
}

// ---- core[e][f] = sum_d tv[d] * k[d][e][f] ----
__global__ __launch_bounds__(1024) void k_core(const float* __restrict__ timevec,
                                               const float* __restrict__ kk,
                                               const int* __restrict__ tind,
                                               float* __restrict__ core) {
  const int e = threadIdx.x >> 5, f = threadIdx.x & 31;
  const float* tv = timevec + (size_t)tind[0] * DD;
  float acc = 0.f;
#pragma unroll
  for (int d = 0; d < DD; ++d) acc += tv[d] * kk[(d * DD + e) * DD + f];
  core[e * DD + f] = acc;
}

// ---- nv2 -> bf16 ----
__global__ __launch_bounds__(256) void k_cvt(const float* __restrict__ src,
                                             unsigned short* __restrict__ dst) {
  const int i = blockIdx.x * 256 + threadIdx.x;
  dst[i] = f2bf(src[i]);
}

// ---- t1[n][f] = sum_e nv1[n][e] * core[e][f]  (bf16 out) ----
__global__ __launch_bounds__(256) void k_t1(const float* __restrict__ nv1,
                                            const float* __restrict__ core,
                                            unsigned short* __restrict__ t1b) {
  __shared__ float cs[1024];
  const int tid = threadIdx.x;
  for (int i = tid; i < 1024; i += 256) cs[i] = core[i];
  __syncthreads();
  const int n = blockIdx.x * 8 + (tid >> 5);
  const int f = tid & 31;
  const float* nr = nv1 + (size_t)n * DD;
  float acc = 0.f;
#pragma unroll
  for (int e = 0; e < DD; ++e) acc += nr[e] * cs[e * DD + f];
  t1b[(size_t)n * DD + f] = f2bf(acc);
}

// ---- sinv[n] = 1 / sum_m exp(relu(t1[n].nv2[m]))  via MFMA logits ----
// block: 4 waves; wave (wsub,mhalf): n-sub 16 rows, half the m range.
__global__ __launch_bounds__(256) void k_stats(const unsigned short* __restrict__ t1b,
                                               const unsigned short* __restrict__ nv2b,
                                               float* __restrict__ sinv) {
  const int tid = threadIdx.x;
  const int w = tid >> 6, lane = tid & 63, q = lane >> 4, i16 = lane & 15;
  const int wsub = w & 1, mhalf = w >> 1;
  const int nblock = blockIdx.x * 32;
  const int nbase = nblock + wsub * 16;
  // A-frag: A[n-local = lane&15][k = q*8+j] = t1[nbase+i16][k]
  bf16x8 a = *(const bf16x8*)(t1b + (size_t)(nbase + i16) * DD + q * 8);
  const f32x4 z4 = {0.f, 0.f, 0.f, 0.f};
  float a0 = 0.f, a1 = 0.f, a2 = 0.f, a3 = 0.f;
  const int m0 = mhalf * 4096;
  for (int mt = m0; mt < m0 + 4096; mt += 16) {
    // B-frag: B[k][m-local = lane&15] = nv2[mt+i16][k]
    bf16x8 b = *(const bf16x8*)(nv2b + (size_t)(mt + i16) * DD + q * 8);
    f32x4 d = __builtin_amdgcn_mfma_f32_16x16x32_bf16(a, b, z4, 0, 0, 0);
    // D: lane holds (n-local = q*4+r, m = mt + i16)
    a0 += __expf(fmaxf(d[0], 0.f));
    a1 += __expf(fmaxf(d[1], 0.f));
    a2 += __expf(fmaxf(d[2], 0.f));
    a3 += __expf(fmaxf(d[3], 0.f));
  }
  // reduce over the 16 m-residue lanes (xor within 16-lane groups)
  for (int off = 1; off < 16; off <<= 1) {
    a0 += __shfl_xor(a0, off, 64);
    a1 += __shfl_xor(a1, off, 64);
    a2 += __shfl_xor(a2, off, 64);
    a3 += __shfl_xor(a3, off, 64);
  }
  __shared__ float part[2][32];
  if (i16 == 0) {
    part[mhalf][wsub * 16 + q * 4 + 0] = a0;
    part[mhalf][wsub * 16 + q * 4 + 1] = a1;
    part[mhalf][wsub * 16 + q * 4 + 2] = a2;
    part[mhalf][wsub * 16 + q * 4 + 3] = a3;
  }
  __syncthreads();
  if (tid < 32) sinv[nblock + tid] = 1.0f / (part[0][tid] + part[1][tid]);
}

// ---- yT[c][n] = bf16(sinv[n] * x[bc][n][t]),  c = bc*12 + t ----
__global__ __launch_bounds__(256) void k_y(const float* __restrict__ x,
                                           const float* __restrict__ sinv,
                                           unsigned short* __restrict__ yT) {
  const int n = blockIdx.x * 256 + threadIdx.x;
  const int c = blockIdx.y;
  const int bc = c / TT, t = c - bc * TT;
  float v = x[((size_t)bc * NN + n) * TT + t] * sinv[n];
  yT[(size_t)c * NN + n] = f2bf(v);
}

// ---- main: out[m,col] += sum_n exp(relu(logit[n,m])) * yT[col][n] ----
// grid (256 m-blocks, 2 k-halves); block 4 waves.
// wave w: E-compute subtile (msub=w&1, nsub=w>>1); accumulate msub{0,1} x coltiles {3w..3w+2}.
__global__ __launch_bounds__(256) void k_main(const unsigned short* __restrict__ t1b,
                                              const unsigned short* __restrict__ nv2b,
                                              const unsigned short* __restrict__ yT,
                                              float* __restrict__ out) {
  const int tid = threadIdx.x;
  const int w = tid >> 6, lane = tid & 63, q = lane >> 4, i16 = lane & 15;
  const int mblock = blockIdx.x * 32;
  const int khalf = blockIdx.y;
  const int msub_w = w & 1, nsub_w = w >> 1;

  __shared__ unsigned short E_lds[32 * 40];  // [m 0..31][n 0..31], stride 40 (80B rows, 16B-aligned)

  // A-frag for logit MFMA: nv2 rows of this block's m-tile (loop-invariant)
  bf16x8 a_nv2 = *(const bf16x8*)(nv2b + (size_t)(mblock + msub_w * 16 + i16) * DD + q * 8);

  f32x4 acc[2][3];
#pragma unroll
  for (int a = 0; a < 2; ++a)
#pragma unroll
    for (int b = 0; b < 3; ++b) acc[a][b] = (f32x4){0.f, 0.f, 0.f, 0.f};
  const f32x4 z4 = {0.f, 0.f, 0.f, 0.f};

  const int nt0 = khalf * 4096;
  for (int nt = nt0; nt < nt0 + 4096; nt += 32) {
    // logit tile: D[m-local][n-local] = sum_k nv2[m][k] t1[n][k]
    bf16x8 b_t1 = *(const bf16x8*)(t1b + (size_t)(nt + nsub_w * 16 + i16) * DD + q * 8);
    f32x4 d = __builtin_amdgcn_mfma_f32_16x16x32_bf16(a_nv2, b_t1, z4, 0, 0, 0);
    __syncthreads();  // prior iteration's E_lds reads complete
#pragma unroll
    for (int r = 0; r < 4; ++r) {
      float e = __expf(fmaxf(d[r], 0.f));
      E_lds[(msub_w * 16 + q * 4 + r) * 40 + (nsub_w * 16 + i16)] = f2bf(e);
    }
    __syncthreads();
    // A-frags: A[m-local = i16][k = n-local = q*8+j]
    bf16x8 afr0 = *(const bf16x8*)&E_lds[(i16) * 40 + q * 8];
    bf16x8 afr1 = *(const bf16x8*)&E_lds[(16 + i16) * 40 + q * 8];
#pragma unroll
    for (int ctl = 0; ctl < 3; ++ctl) {
      const int ct = w * 3 + ctl;
      // B-frag: B[k = q*8+j][col-local = i16] = yT[ct*16+i16][nt + q*8 + j]
      bf16x8 bfr = *(const bf16x8*)(yT + (size_t)(ct * 16 + i16) * NN + nt + q * 8);
      acc[0][ctl] = __builtin_amdgcn_mfma_f32_16x16x32_bf16(afr0, bfr, acc[0][ctl], 0, 0, 0);
      acc[1][ctl] = __builtin_amdgcn_mfma_f32_16x16x32_bf16(afr1, bfr, acc[1][ctl], 0, 0, 0);
    }
  }

#pragma unroll
  for (int msub = 0; msub < 2; ++msub)
#pragma unroll
    for (int ctl = 0; ctl < 3; ++ctl) {
      const int ct = w * 3 + ctl;
      const int col = ct * 16 + i16;
      const int bc = col / TT;
      const int t = col - bc * TT;
#pragma unroll
      for (int r = 0; r < 4; ++r) {
        const int m = mblock + msub * 16 + q * 4 + r;
        atomicAdd(&out[((size_t)bc * NN + m) * TT + t], acc[msub][ctl][r]);
      }
    }
}

extern "C" void kernel_launch(void* const* d_in, const int* in_sizes, int n_in,
                              void* d_out, int out_size, void* d_ws, size_t ws_size,
                              hipStream_t stream) {
  const float* x = (const float*)d_in[0];
  const float* nv1 = (const float*)d_in[1];
  const float* nv2 = (const float*)d_in[2];
  const float* tv = (const float*)d_in[3];
  const float* kk = (const float*)d_in[4];
  const int* tind = (const int*)d_in[5];
  float* out = (float*)d_out;

  char* ws = (char*)d_ws;
  float* core = (float*)(ws);                         //    4096 B
  unsigned short* t1b = (unsigned short*)(ws + 4096); //  524288 B
  unsigned short* nv2b = (unsigned short*)(ws + 528384);   // 524288 B
  float* sinv = (float*)(ws + 1052672);               //   32768 B
  unsigned short* yT = (unsigned short*)(ws + 1085440);    // 3145728 B  (total ~4.04 MB)

  hipMemsetAsync(d_out, 0, (size_t)out_size * sizeof(float), stream);
  k_core<<<1, 1024, 0, stream>>>(tv, kk, tind, core);
  k_cvt<<<1024, 256, 0, stream>>>(nv2, nv2b);
  k_t1<<<1024, 256, 0, stream>>>(nv1, core, t1b);
  k_stats<<<256, 256, 0, stream>>>(t1b, nv2b, sinv);
  k_y<<<dim3(32, 192), 256, 0, stream>>>(x, sinv, yT);
  k_main<<<dim3(256, 2), 256, 0, stream>>>(t1b, nv2b, yT, out);
}